// Round 11
// baseline (455.637 us; speedup 1.0000x reference)
//
#include <hip/hip_runtime.h>
#include <math.h>

#define NB   8
#define NW   200
#define NK   100
#define KSZ  7
#define NHID 150
#define NFE  400
#define NTE  200
#define NG   450   // 3*HID
#define NCIN 300   // 3*K
#define ALPHAC 0.2f

typedef __attribute__((ext_vector_type(8))) short bf8;
typedef __attribute__((ext_vector_type(4))) float f32x4;

__device__ __forceinline__ float sigmoidf_(float x){
  return 1.0f/(1.0f + __expf(-x));
}
__device__ __forceinline__ float tanhf_(float x){
  float xc = fminf(fmaxf(x, -15.f), 15.f);
  float e = __expf(2.f*xc);
  return (e - 1.f)/(e + 1.f);
}
__device__ __forceinline__ unsigned short f2bf(float f){
  unsigned int u = __float_as_uint(f);
  unsigned int r = u + 0x7FFFu + ((u>>16)&1u);
  return (unsigned short)(r>>16);
}
__device__ __forceinline__ float lrelu_(float x){
  return fmaxf(x, 0.f) + ALPHAC*fminf(x, 0.f);
}

// ---------------- weight prep ----------------
// A-fragments (weights) for swapped-operand GRU MFMA: 32 tiles x 5 K x 64 lanes x 4 dw.
// Matrix row m = lane&15 = PERMUTED weight-column; k = ks*32 + (lane>>4)*8 + 2d (+0/1).
// Permutation: tile = w + 8*tidx; m = 4g + r; p = r*4 + tidx; p<15: q=p/3, gam=p%3,
// s = w*20 + g*5 + q; GRU col = gam*150 + s (s<150), else zero.
__global__ void prep_kernel(const float* conv_w, const float* w_ih, const float* w_hh,
                            float* conv_wT, float* w_ihT, unsigned int* Bfrag){
  int idx = blockIdx.x*256 + threadIdx.x;
  const int n1 = NK*NK*KSZ;      // 70000
  const int n2 = NG*NCIN;        // 135000
  const int n3 = 32*5*64*4;      // 40960 dwords
  if (idx < n1){
    int k = idx % NK; int it = idx / NK;       // it = i*KSZ + t
    int i = it / KSZ, t = it % KSZ;
    conv_wT[idx] = conv_w[(k*NK + i)*KSZ + t];
  } else if (idx < n1 + n2){
    int o = idx - n1; int g = o % NG; int c = o / NG;
    w_ihT[o] = w_ih[g*NCIN + c];
  } else if (idx < n1 + n2 + n3){
    int o = idx - n1 - n2;
    int ntile = o / 1280;
    int rem  = o % 1280;
    int ks   = rem / 256;
    int rem2 = rem % 256;
    int l    = rem2 >> 2;
    int d    = rem2 & 3;
    int w    = ntile & 7;
    int tidx = ntile >> 3;
    int m    = l & 15;
    int gm   = m >> 2;
    int r    = m & 3;
    int p    = r*4 + tidx;
    int col  = -1;
    if (p < 15){
      int q = p/3, gam = p%3;
      int s = w*20 + gm*5 + q;
      if (s < NHID) col = gam*NHID + s;
    }
    int k0 = ks*32 + (l >> 4)*8 + d*2;
    unsigned short lo = 0, hi = 0;
    if (col >= 0){
      if (k0     < NHID) lo = f2bf(w_hh[col*NHID + k0]);
      if (k0 + 1 < NHID) hi = f2bf(w_hh[col*NHID + k0 + 1]);
    }
    Bfrag[o] = ((unsigned int)hi << 16) | lo;
  }
}

// ---------------- conv1d + bias + relu -> xc (B,W,K) ----------------
__global__ void conv_kernel(const float* x, const float* conv_b, const float* conv_wT, float* xc){
  int idx = blockIdx.x*256 + threadIdx.x;
  if (idx >= NB*NW*NK) return;
  int k = idx % NK; int w = (idx/NK) % NW; int b = idx/(NK*NW);
  float acc = conv_b[k];
  const float* xb = x + b*NW*NK;
  for (int t = 0; t < KSZ; ++t){
    int ws = w + t - 3;
    if (ws < 0 || ws >= NW) continue;
    const float* xr = xb + ws*NK;
    const float* wr = conv_wT + t*NK + k;   // (i*KSZ+t)*NK + k
    #pragma unroll 4
    for (int i = 0; i < NK; ++i){
      acc += xr[i] * wr[i*KSZ*NK];
    }
  }
  xc[idx] = fmaxf(acc, 0.0f);
}

// ---------------- fused si/sj kernel: blocks 0..199 f-GAT, 200..599 t-GAT ----------------
__global__ void sisj_fused(const float* xc, const float* f_lin_w, float* si_f, float* sj_f,
                           const float* t_lin_w, float* si_t, float* sj_t){
  __shared__ __align__(16) float vt[NW*4];
  int tid = threadIdx.x;
  if (blockIdx.x < 200){
    int b = blockIdx.x / 25; int n0 = (blockIdx.x % 25)*4;
    for (int d = tid; d < NW; d += 512){
      float4 v = *(const float4*)&xc[(b*NW + d)*NK + n0];
      *(float4*)&vt[d*4] = v;
    }
    __syncthreads();
    if (tid >= NFE) return;
    int e = tid;
    float a1[4] = {0,0,0,0}, a2[4] = {0,0,0,0};
    for (int d = 0; d < NW; ++d){
      float w1 = f_lin_w[d*NFE + e];
      float w2 = f_lin_w[(NW + d)*NFE + e];
      float4 v = *(const float4*)&vt[d*4];
      a1[0] += v.x*w1; a1[1] += v.y*w1; a1[2] += v.z*w1; a1[3] += v.w*w1;
      a2[0] += v.x*w2; a2[1] += v.y*w2; a2[2] += v.z*w2; a2[3] += v.w*w2;
    }
    #pragma unroll
    for (int nn = 0; nn < 4; ++nn){
      si_f[(b*NK + n0+nn)*NFE + e] = a1[nn];
      sj_f[(b*NK + n0+nn)*NFE + e] = a2[nn];
    }
  } else {
    int bi = blockIdx.x - 200;
    int b = bi / 50; int n0 = (bi % 50)*4;
    for (int idx = tid; idx < 4*25; idx += 512){
      int nn = idx & 3; int d4 = idx >> 2;
      float4 v = *(const float4*)&xc[(b*NW + n0+nn)*NK + d4*4];
      vt[(d4*4+0)*4 + nn] = v.x;
      vt[(d4*4+1)*4 + nn] = v.y;
      vt[(d4*4+2)*4 + nn] = v.z;
      vt[(d4*4+3)*4 + nn] = v.w;
    }
    __syncthreads();
    if (tid >= NTE) return;
    int e = tid;
    float a1[4] = {0,0,0,0}, a2[4] = {0,0,0,0};
    for (int d = 0; d < NK; ++d){
      float w1 = t_lin_w[d*NTE + e];
      float w2 = t_lin_w[(NK + d)*NTE + e];
      float4 v = *(const float4*)&vt[d*4];
      a1[0] += v.x*w1; a1[1] += v.y*w1; a1[2] += v.z*w1; a1[3] += v.w*w1;
      a2[0] += v.x*w2; a2[1] += v.y*w2; a2[2] += v.z*w2; a2[3] += v.w*w2;
    }
    #pragma unroll
    for (int nn = 0; nn < 4; ++nn){
      si_t[(b*NW + n0+nn)*NTE + e] = a1[nn];
      sj_t[(b*NW + n0+nn)*NTE + e] = a2[nn];
    }
  }
}

// ---------------- fused attention: blocks 0..799 f-GAT, 800..2399 t-GAT ----------------
__global__ void attn_fused(const float* xc,
                           const float* si_f, const float* sj_f, const float* f_lin_b,
                           const float* f_a, const float* f_bias,
                           const float* si_t, const float* sj_t, const float* t_lin_b,
                           const float* t_a, const float* t_bias,
                           float* h_featT, float* h_temp){
  __shared__ __align__(16) float sib[NFE];
  __shared__ __align__(16) float av[NFE];
  __shared__ __align__(16) float attn[NW];
  __shared__ float red[8];
  int tid = threadIdx.x, lane = tid & 63, wid = tid >> 6;
  if (blockIdx.x < NB*NK){
    int b = blockIdx.x / NK, i = blockIdx.x % NK;
    {
      const float4* si4 = (const float4*)(si_f + (b*NK + i)*NFE);
      const float4* lb4 = (const float4*)f_lin_b;
      const float4* fa4 = (const float4*)f_a;
      for (int e4 = tid; e4 < NFE/4; e4 += 256){
        float4 s = si4[e4], l = lb4[e4];
        float4 o; o.x=s.x+l.x; o.y=s.y+l.y; o.z=s.z+l.z; o.w=s.w+l.w;
        *(float4*)&sib[e4*4] = o;
        *(float4*)&av[e4*4]  = fa4[e4];
      }
    }
    __syncthreads();
    float ej = -1e30f;
    if (tid < NK){
      const float4* sjr4 = (const float4*)(sj_f + (b*NK + tid)*NFE);
      const float4* sib4 = (const float4*)sib;
      const float4* av4  = (const float4*)av;
      float acc = 0.f;
      #pragma unroll 4
      for (int e4 = 0; e4 < NFE/4; ++e4){
        float4 s = sjr4[e4], t = sib4[e4], a = av4[e4];
        acc += a.x*lrelu_(t.x+s.x) + a.y*lrelu_(t.y+s.y)
             + a.z*lrelu_(t.z+s.z) + a.w*lrelu_(t.w+s.w);
      }
      ej = acc + f_bias[i*NK + tid];
    }
    float m = ej;
    #pragma unroll
    for (int off = 32; off > 0; off >>= 1) m = fmaxf(m, __shfl_xor(m, off));
    if (lane == 0) red[wid] = m;
    __syncthreads();
    float bm = fmaxf(fmaxf(red[0], red[1]), fmaxf(red[2], red[3]));
    float ex = (tid < NK) ? __expf(ej - bm) : 0.f;
    float s = ex;
    #pragma unroll
    for (int off = 32; off > 0; off >>= 1) s += __shfl_xor(s, off);
    if (lane == 0) red[4 + wid] = s;
    __syncthreads();
    float denom = red[4] + red[5] + red[6] + red[7];
    if (tid < NK) attn[tid] = ex / denom;
    __syncthreads();
    for (int d = tid; d < NW; d += 256){
      const float4* xr4 = (const float4*)(xc + (b*NW + d)*NK);
      const float4* at4 = (const float4*)attn;
      float acc = 0.f;
      #pragma unroll 5
      for (int j4 = 0; j4 < NK/4; ++j4){
        float4 v = xr4[j4], a = at4[j4];
        acc += a.x*v.x + a.y*v.y + a.z*v.z + a.w*v.w;
      }
      h_featT[(b*NW + d)*NK + i] = sigmoidf_(acc);
    }
  } else {
    int bi = blockIdx.x - NB*NK;
    int b = bi / NW, i = bi % NW;
    {
      const float4* si4 = (const float4*)(si_t + (b*NW + i)*NTE);
      const float4* lb4 = (const float4*)t_lin_b;
      const float4* ta4 = (const float4*)t_a;
      for (int e4 = tid; e4 < NTE/4; e4 += 256){
        float4 s = si4[e4], l = lb4[e4];
        float4 o; o.x=s.x+l.x; o.y=s.y+l.y; o.z=s.z+l.z; o.w=s.w+l.w;
        *(float4*)&sib[e4*4] = o;
        *(float4*)&av[e4*4]  = ta4[e4];
      }
    }
    __syncthreads();
    float ej = -1e30f;
    if (tid < NW){
      const float4* sjr4 = (const float4*)(sj_t + (b*NW + tid)*NTE);
      const float4* sib4 = (const float4*)sib;
      const float4* av4  = (const float4*)av;
      float acc = 0.f;
      #pragma unroll 4
      for (int e4 = 0; e4 < NTE/4; ++e4){
        float4 s = sjr4[e4], t = sib4[e4], a = av4[e4];
        acc += a.x*lrelu_(t.x+s.x) + a.y*lrelu_(t.y+s.y)
             + a.z*lrelu_(t.z+s.z) + a.w*lrelu_(t.w+s.w);
      }
      ej = acc + t_bias[i*NW + tid];
    }
    float m = ej;
    #pragma unroll
    for (int off = 32; off > 0; off >>= 1) m = fmaxf(m, __shfl_xor(m, off));
    if (lane == 0) red[wid] = m;
    __syncthreads();
    float bm = fmaxf(fmaxf(red[0], red[1]), fmaxf(red[2], red[3]));
    float ex = (tid < NW) ? __expf(ej - bm) : 0.f;
    float s = ex;
    #pragma unroll
    for (int off = 32; off > 0; off >>= 1) s += __shfl_xor(s, off);
    if (lane == 0) red[4 + wid] = s;
    __syncthreads();
    float denom = red[4] + red[5] + red[6] + red[7];
    if (tid < NW) attn[tid] = ex / denom;
    __syncthreads();
    for (int d = tid; d < NK; d += 256){
      float acc = 0.f;
      #pragma unroll 4
      for (int j = 0; j < NW; ++j) acc += attn[j]*xc[(b*NW + j)*NK + d];
      h_temp[(b*NW + i)*NK + d] = sigmoidf_(acc);
    }
  }
}

// ---------------- gi (permuted slot layout) = h_cat @ w_ih^T + b_ih (+b_hh r/z) ----------------
// output layout: gi_p[((t*160 + u)*3 + gam)*8 + b]  (u = hidden idx = slot s)
__global__ void gi_kernel(const float* xc, const float* h_featT, const float* h_temp,
                          const float* w_ihT, const float* b_ih, const float* b_hh, float* gi_p){
  __shared__ __align__(16) float hc[NCIN*8];   // [c][tt], stride 8
  int b = blockIdx.x / 25; int t0 = (blockIdx.x % 25)*8;
  int tid = threadIdx.x;
  for (int idx = tid; idx < NCIN*8; idx += 512){
    int tt = idx / NCIN; int c = idx % NCIN;
    int base = (b*NW + t0 + tt)*NK;
    float v;
    if (c < NK)        v = xc[base + c];
    else if (c < 2*NK) v = h_featT[base + c - NK];
    else               v = h_temp[base + c - 2*NK];
    hc[c*8 + tt] = v;
  }
  __syncthreads();
  if (tid >= NG) return;
  int g = tid;
  float bi = b_ih[g] + ((g < 2*NHID) ? b_hh[g] : 0.f);
  float acc[8];
  #pragma unroll
  for (int tt = 0; tt < 8; ++tt) acc[tt] = bi;
  for (int c = 0; c < NCIN; ++c){
    float wv = w_ihT[c*NG + g];
    float4 h0 = *(const float4*)&hc[c*8];
    float4 h1 = *(const float4*)&hc[c*8+4];
    acc[0] += h0.x*wv; acc[1] += h0.y*wv; acc[2] += h0.z*wv; acc[3] += h0.w*wv;
    acc[4] += h1.x*wv; acc[5] += h1.y*wv; acc[6] += h1.z*wv; acc[7] += h1.w*wv;
  }
  int gam = (g < NHID) ? 0 : ((g < 2*NHID) ? 1 : 2);
  int u = g - gam*NHID;
  #pragma unroll
  for (int tt = 0; tt < 8; ++tt)
    gi_p[(((t0+tt)*160 + u)*3 + gam)*8 + b] = acc[tt];
}

// ---------------- sequential GRU: swapped-operand MFMA, in-register gates, 1 barrier/step ----------------
// A = weights (AGPR, column-permuted), B = h (16 slots: col 2b=hi, 2b+1=lo).
// C[m=weight-col][n=slot]: lane(g,n) holds 16 cols = 5 gate-triples for batch n>>1.
// shfl_xor(1) folds hi+lo; gates run in-register; h round-trips via double-buffered LDS.
#define STASH(B0,B1,B2,B3, FR) { \
  int4 wq = Bq[(FR)*64 + lane]; \
  asm volatile("v_accvgpr_write_b32 " B0 ", %0\n\t" \
               "v_accvgpr_write_b32 " B1 ", %1\n\t" \
               "v_accvgpr_write_b32 " B2 ", %2\n\t" \
               "v_accvgpr_write_b32 " B3 ", %3" \
               :: "v"(wq.x), "v"(wq.y), "v"(wq.z), "v"(wq.w) \
               : B0, B1, B2, B3); }
#define MMA_INIT(ACC, AR, BF, C0,C1,C2,C3) \
  asm volatile("v_mfma_f32_16x16x32_bf16 %0, " AR ", %1, 0" \
               : "=v"(ACC) : "v"(BF) : C0,C1,C2,C3);
#define MMA_ACC(ACC, AR, BF, C0,C1,C2,C3) \
  asm volatile("v_mfma_f32_16x16x32_bf16 %0, " AR ", %1, %0" \
               : "+v"(ACC) : "v"(BF) : C0,C1,C2,C3);

__device__ __forceinline__ void pack_hilo(float hn, unsigned int& hi2, unsigned int& lo2){
  asm("v_cvt_pk_bf16_f32 %0, %1, %1" : "=v"(hi2) : "v"(hn));
  float hif = __uint_as_float(hi2 << 16);
  float lo = hn - hif;
  asm("v_cvt_pk_bf16_f32 %0, %1, %1" : "=v"(lo2) : "v"(lo));
}

__global__ void __launch_bounds__(512) gru_kernel(const float* gi_p, const int4* Bq,
                                                  const float* b_hh, float* out){
  __shared__ __align__(16) unsigned short h_b0[16*168];  // [slot][21 kgrp][8], slot 2b=hi,2b+1=lo
  __shared__ __align__(16) unsigned short h_b1[16*168];
  int tid = threadIdx.x;
  int lane = tid & 63;
  int wv = tid >> 6;            // 0..7
  int g  = lane >> 4;           // 0..3
  int n  = lane & 15;           // batch-slot (2b / 2b+1)
  int b  = n >> 1;
  int P  = n & 1;               // parity: owns triples q={3,4} (P=1) or {0,1,2} (P=0)

  int s0 = wv*20 + g*5 + (P ? 3 : 0);
  int s1 = s0 + 1;
  int s2 = s0 + 2;              // only meaningful for P==0
  bool v0 = (s0 < NHID);
  bool v1 = (s1 < NHID);
  bool v2 = (P == 0) && (s2 < NHID);

  float bhn0 = b_hh[2*NHID + (v0 ? s0 : 0)];
  float bhn1 = b_hh[2*NHID + (v1 ? s1 : 0)];
  float bhn2 = b_hh[2*NHID + (v2 ? s2 : 0)];

  // stash A-fragments (weights): tiles wv, wv+8, wv+16, wv+24; 5 K-steps -> a0..a79
  STASH("a0","a1","a2","a3",     (wv)*5+0)
  STASH("a4","a5","a6","a7",     (wv)*5+1)
  STASH("a8","a9","a10","a11",   (wv)*5+2)
  STASH("a12","a13","a14","a15", (wv)*5+3)
  STASH("a16","a17","a18","a19", (wv)*5+4)
  STASH("a20","a21","a22","a23", (wv+8)*5+0)
  STASH("a24","a25","a26","a27", (wv+8)*5+1)
  STASH("a28","a29","a30","a31", (wv+8)*5+2)
  STASH("a32","a33","a34","a35", (wv+8)*5+3)
  STASH("a36","a37","a38","a39", (wv+8)*5+4)
  STASH("a40","a41","a42","a43", (wv+16)*5+0)
  STASH("a44","a45","a46","a47", (wv+16)*5+1)
  STASH("a48","a49","a50","a51", (wv+16)*5+2)
  STASH("a52","a53","a54","a55", (wv+16)*5+3)
  STASH("a56","a57","a58","a59", (wv+16)*5+4)
  STASH("a60","a61","a62","a63", (wv+24)*5+0)
  STASH("a64","a65","a66","a67", (wv+24)*5+1)
  STASH("a68","a69","a70","a71", (wv+24)*5+2)
  STASH("a72","a73","a74","a75", (wv+24)*5+3)
  STASH("a76","a77","a78","a79", (wv+24)*5+4)

  for (int i = tid; i < 16*168; i += 512){ h_b0[i] = 0; h_b1[i] = 0; }
  __syncthreads();

  int rb_base = n*21 + g;       // bf8 units; +4 per K-step

  // h write addresses (shorts): hi -> slot 2b, lo -> slot 2b+1, k = s
  int wa0h = (2*b)*168   + (s0>>3)*8 + (s0&7);
  int wa0l = wa0h + 168;
  int wa1h = (2*b)*168   + (s1>>3)*8 + (s1&7);
  int wa1l = wa1h + 168;
  int wa2h = (2*b)*168   + (s2>>3)*8 + (s2&7);
  int wa2l = wa2h + 168;

  float hold0 = 0.f, hold1 = 0.f, hold2 = 0.f;

  // gi pointer: [t][s][gam][b]; triple stride 96B, gam stride 32B
  const float* gp = gi_p + (s0*3)*8 + b;
  float cr0 = gp[0],  cz0 = gp[8],  cn0 = gp[16];
  float cr1 = gp[24], cz1 = gp[32], cn1 = gp[40];
  float cr2 = gp[48], cz2 = gp[56], cn2 = gp[64];

  for (int t = 0; t < NW; ++t){
    const unsigned short* rbuf = (t & 1) ? h_b1 : h_b0;
    unsigned short*       wbuf = (t & 1) ? h_b0 : h_b1;

    // prefetch next step's gi
    gp += 160*3*8;
    float nr0 = gp[0],  nz0 = gp[8],  nn0 = gp[16];
    float nr1 = gp[24], nz1 = gp[32], nn1 = gp[40];
    float nr2 = gp[48], nz2 = gp[56], nn2 = gp[64];

    const bf8* HB = (const bf8*)rbuf;
    bf8 B0 = HB[rb_base],    B1 = HB[rb_base+4],  B2 = HB[rb_base+8],
        B3 = HB[rb_base+12], B4 = HB[rb_base+16];

    f32x4 c0, c1, c2, c3;
    MMA_INIT(c0, "a[0:3]",   B0, "a0","a1","a2","a3")
    MMA_INIT(c1, "a[20:23]", B0, "a20","a21","a22","a23")
    MMA_INIT(c2, "a[40:43]", B0, "a40","a41","a42","a43")
    MMA_INIT(c3, "a[60:63]", B0, "a60","a61","a62","a63")
    MMA_ACC (c0, "a[4:7]",   B1, "a4","a5","a6","a7")
    MMA_ACC (c1, "a[24:27]", B1, "a24","a25","a26","a27")
    MMA_ACC (c2, "a[44:47]", B1, "a44","a45","a46","a47")
    MMA_ACC (c3, "a[64:67]", B1, "a64","a65","a66","a67")
    MMA_ACC (c0, "a[8:11]",  B2, "a8","a9","a10","a11")
    MMA_ACC (c1, "a[28:31]", B2, "a28","a29","a30","a31")
    MMA_ACC (c2, "a[48:51]", B2, "a48","a49","a50","a51")
    MMA_ACC (c3, "a[68:71]", B2, "a68","a69","a70","a71")
    MMA_ACC (c0, "a[12:15]", B3, "a12","a13","a14","a15")
    MMA_ACC (c1, "a[32:35]", B3, "a32","a33","a34","a35")
    MMA_ACC (c2, "a[52:55]", B3, "a52","a53","a54","a55")
    MMA_ACC (c3, "a[72:75]", B3, "a72","a73","a74","a75")
    MMA_ACC (c0, "a[16:19]", B4, "a16","a17","a18","a19")
    MMA_ACC (c1, "a[36:39]", B4, "a36","a37","a38","a39")
    MMA_ACC (c2, "a[56:59]", B4, "a56","a57","a58","a59")
    MMA_ACC (c3, "a[76:79]", B4, "a76","a77","a78","a79")
    asm volatile("s_nop 7\n\ts_nop 7" ::: );   // MFMA->VALU hazard

    // fold hi+lo across slot pair (both lanes get the sum)
    float f00=c0[0]; f00 += __shfl_xor(f00,1);
    float f10=c1[0]; f10 += __shfl_xor(f10,1);
    float f20=c2[0]; f20 += __shfl_xor(f20,1);
    float f30=c3[0]; f30 += __shfl_xor(f30,1);
    float f01=c0[1]; f01 += __shfl_xor(f01,1);
    float f11=c1[1]; f11 += __shfl_xor(f11,1);
    float f21=c2[1]; f21 += __shfl_xor(f21,1);
    float f31=c3[1]; f31 += __shfl_xor(f31,1);
    float f02=c0[2]; f02 += __shfl_xor(f02,1);
    float f12=c1[2]; f12 += __shfl_xor(f12,1);
    float f22=c2[2]; f22 += __shfl_xor(f22,1);
    float f32=c3[2]; f32 += __shfl_xor(f32,1);
    float f03=c0[3]; f03 += __shfl_xor(f03,1);
    float f13=c1[3]; f13 += __shfl_xor(f13,1);
    float f23=c2[3]; f23 += __shfl_xor(f23,1);

    // branch-free triple selection: P=0 -> q{0,1,2}, P=1 -> q{3,4}
    float ghr0 = P ? f12 : f00, ghz0 = P ? f22 : f10, ghn0 = P ? f32 : f20;
    float ghr1 = P ? f03 : f30, ghz1 = P ? f13 : f01, ghn1 = P ? f23 : f11;
    float ghr2 = f21,           ghz2 = f31,           ghn2 = f02;

    // gates (pure register math)
    {
      float r = sigmoidf_(cr0 + ghr0);
      float z = sigmoidf_(cz0 + ghz0);
      float nn = tanhf_ (cn0 + r*(ghn0 + bhn0));
      float hn = (1.f - z)*nn + z*hold0;
      hold0 = hn;
      if (v0){ unsigned int h2,l2; pack_hilo(hn,h2,l2);
               wbuf[wa0h]=(unsigned short)h2; wbuf[wa0l]=(unsigned short)l2; }
    }
    {
      float r = sigmoidf_(cr1 + ghr1);
      float z = sigmoidf_(cz1 + ghz1);
      float nn = tanhf_ (cn1 + r*(ghn1 + bhn1));
      float hn = (1.f - z)*nn + z*hold1;
      hold1 = hn;
      if (v1){ unsigned int h2,l2; pack_hilo(hn,h2,l2);
               wbuf[wa1h]=(unsigned short)h2; wbuf[wa1l]=(unsigned short)l2; }
    }
    {
      float r = sigmoidf_(cr2 + ghr2);
      float z = sigmoidf_(cz2 + ghz2);
      float nn = tanhf_ (cn2 + r*(ghn2 + bhn2));
      float hn = (1.f - z)*nn + z*hold2;
      hold2 = hn;
      if (v2){ unsigned int h2,l2; pack_hilo(hn,h2,l2);
               wbuf[wa2h]=(unsigned short)h2; wbuf[wa2l]=(unsigned short)l2; }
    }
    __syncthreads();   // the ONLY barrier: writes(t) -> reads(t+1)

    cr0 = nr0; cz0 = nz0; cn0 = nn0;
    cr1 = nr1; cz1 = nz1; cn1 = nn1;
    cr2 = nr2; cz2 = nz2; cn2 = nn2;
  }

  if (v0) out[b*NHID + s0] = hold0;
  if (v1) out[b*NHID + s1] = hold1;
  if (v2) out[b*NHID + s2] = hold2;
}

extern "C" void kernel_launch(void* const* d_in, const int* in_sizes, int n_in,
                              void* d_out, int out_size, void* d_ws, size_t ws_size,
                              hipStream_t stream){
  const float* x       = (const float*)d_in[0];
  const float* conv_w  = (const float*)d_in[1];
  const float* conv_b  = (const float*)d_in[2];
  const float* f_lin_w = (const float*)d_in[3];
  const float* f_lin_b = (const float*)d_in[4];
  const float* f_a     = (const float*)d_in[5];
  const float* f_bias  = (const float*)d_in[6];
  const float* t_lin_w = (const float*)d_in[7];
  const float* t_lin_b = (const float*)d_in[8];
  const float* t_a     = (const float*)d_in[9];
  const float* t_bias  = (const float*)d_in[10];
  const float* w_ih    = (const float*)d_in[11];
  const float* w_hh    = (const float*)d_in[12];
  const float* b_ih    = (const float*)d_in[13];
  const float* b_hh    = (const float*)d_in[14];

  float* ws      = (float*)d_ws;
  float* xc      = ws;               // 160000
  float* conv_wT = ws + 160000;      // 70000
  float* si_f    = ws + 230000;      // 320000
  float* sj_f    = ws + 550000;      // 320000
  float* h_featT = ws + 870000;      // 160000
  float* si_t    = ws + 1030000;     // 320000
  float* sj_t    = ws + 1350000;     // 320000
  float* h_temp  = ws + 1670000;     // 160000
  float* w_ihT   = ws + 1830000;     // 135000
  float* gi_p    = ws + 1965000;     // 768000 (200 x 160 x 3 x 8)
  float* BfragF  = ws + 2733000;     // 40960 dwords (16B-aligned)
                                     // total 2773960 floats ~= 11.1 MB

  prep_kernel<<<961, 256, 0, stream>>>(conv_w, w_ih, w_hh, conv_wT, w_ihT, (unsigned int*)BfragF);
  conv_kernel<<<(NB*NW*NK + 255)/256, 256, 0, stream>>>(x, conv_b, conv_wT, xc);
  sisj_fused<<<600, 512, 0, stream>>>(xc, f_lin_w, si_f, sj_f, t_lin_w, si_t, sj_t);
  attn_fused<<<2400, 256, 0, stream>>>(xc, si_f, sj_f, f_lin_b, f_a, f_bias,
                                       si_t, sj_t, t_lin_b, t_a, t_bias, h_featT, h_temp);
  gi_kernel<<<200, 512, 0, stream>>>(xc, h_featT, h_temp, w_ihT, b_ih, b_hh, gi_p);
  gru_kernel<<<1, 512, 0, stream>>>(gi_p, (const int4*)BfragF, b_hh, (float*)d_out);
}